// Round 1
// baseline (3385.143 us; speedup 1.0000x reference)
//
#include <hip/hip_runtime.h>

#define HIDDEN 450
#define MAX_NB 15
#define N_ATOMS 20000
#define N_BONDS 40000
#define N_MESS  16000
#define N_MOLS  1000
#define BOND_FD 40      // ATOM_FDIM + BOND_FDIM
#define ATOM_FD 35
#define WO_LD   485     // ATOM_FDIM + HIDDEN

#define BM 64
#define BN 64
#define BK 16

// Load a BMxBK (row x k) tile, transposed into S[k][row], zero-padded OOB.
// Scalar loads only: input leading dims (35/40/450/485 floats) are not all
// 16B-aligned per row, so float4 global loads would be UB for odd rows.
__device__ __forceinline__ void load_tile(const float* __restrict__ P, int ld,
                                          int row0, int nrows, int k0, int K,
                                          float (&S)[BK][BM + 4]) {
    const int t = threadIdx.x;
    const int k = t & 15;      // 0..15
    const int r = t >> 4;      // 0..15
#pragma unroll
    for (int i = 0; i < 4; ++i) {
        const int rr = r + 16 * i;
        const int gr = row0 + rr;
        const int gk = k0 + k;
        float v = 0.0f;
        if (gr < nrows && gk < K) v = P[(size_t)gr * ld + gk];
        S[k][rr] = v;
    }
}

// C[m,n] = relu( sum_k A1[m,k]W1[n,k] + sum_k A2[m,k]W2[n,k] (+bias[n]) )
// MODE 0: store to C[m*N+n].  MODE 1: atomicAdd(C[mol_ids[m]*N+n], val).
template <int MODE>
__global__ __launch_bounds__(256) void gemm2(
    const float* __restrict__ A1, int lda1, const float* __restrict__ W1, int ldw1, int K1,
    const float* __restrict__ A2, int lda2, const float* __restrict__ W2, int ldw2, int K2,
    const float* __restrict__ bias, const int* __restrict__ mol_ids,
    float* __restrict__ C, int M, int N) {
    __shared__ float As[BK][BM + 4];
    __shared__ float Ws[BK][BN + 4];
    const int tx = threadIdx.x & 15;
    const int ty = threadIdx.x >> 4;
    const int m0 = blockIdx.x * BM;
    const int n0 = blockIdx.y * BN;
    float acc[4][4] = {};

#pragma unroll 1
    for (int seg = 0; seg < 2; ++seg) {
        const float* A = seg ? A2 : A1;
        const float* W = seg ? W2 : W1;
        const int lda = seg ? lda2 : lda1;
        const int ldw = seg ? ldw2 : ldw1;
        const int K   = seg ? K2 : K1;
        if (A == nullptr || K == 0) continue;   // uniform across block
#pragma unroll 1
        for (int k0 = 0; k0 < K; k0 += BK) {
            load_tile(A, lda, m0, M, k0, K, As);
            load_tile(W, ldw, n0, N, k0, K, Ws);
            __syncthreads();
#pragma unroll
            for (int k = 0; k < BK; ++k) {
                const float4 a4 = *(const float4*)&As[k][ty * 4];
                const float4 b4 = *(const float4*)&Ws[k][tx * 4];
                const float av[4] = {a4.x, a4.y, a4.z, a4.w};
                const float bv[4] = {b4.x, b4.y, b4.z, b4.w};
#pragma unroll
                for (int i = 0; i < 4; ++i)
#pragma unroll
                    for (int j = 0; j < 4; ++j)
                        acc[i][j] = fmaf(av[i], bv[j], acc[i][j]);
            }
            __syncthreads();
        }
    }

#pragma unroll
    for (int i = 0; i < 4; ++i) {
        const int gm = m0 + ty * 4 + i;
        if (gm >= M) continue;
#pragma unroll
        for (int j = 0; j < 4; ++j) {
            const int gn = n0 + tx * 4 + j;
            if (gn >= N) continue;
            float v = acc[i][j];
            if (MODE == 1) v += bias[gn];
            v = fmaxf(v, 0.0f);
            if (MODE == 0)
                C[(size_t)gm * N + gn] = v;
            else
                atomicAdd(&C[(size_t)mol_ids[gm] * N + gn], v);
        }
    }
}

// out[r,:] = sum_j msg[graph[r,j], :] where msg = concat(tree, gmsg) virtually.
__global__ __launch_bounds__(256) void gather_sum(const int* __restrict__ g,
                                                  const float* __restrict__ tree,
                                                  const float* __restrict__ gmsg,
                                                  float* __restrict__ out) {
    const int r = blockIdx.x;
    const int tid = threadIdx.x;
    const int* gr = g + (size_t)r * MAX_NB;
    float acc0 = 0.0f, acc1 = 0.0f;
#pragma unroll 1
    for (int j = 0; j < MAX_NB; ++j) {
        const int idx = gr[j];
        const float* row = (idx < N_MESS) ? (tree + (size_t)idx * HIDDEN)
                                          : (gmsg + (size_t)(idx - N_MESS) * HIDDEN);
        acc0 += row[tid];
        if (tid + 256 < HIDDEN) acc1 += row[tid + 256];
    }
    out[(size_t)r * HIDDEN + tid] = acc0;
    if (tid + 256 < HIDDEN) out[(size_t)r * HIDDEN + tid + 256] = acc1;
}

__global__ __launch_bounds__(256) void count_atoms(const int* __restrict__ mol_ids,
                                                   float* __restrict__ counts) {
    const int a = blockIdx.x * 256 + threadIdx.x;
    if (a < N_ATOMS) atomicAdd(&counts[mol_ids[a]], 1.0f);
}

__global__ __launch_bounds__(256) void div_counts(float* __restrict__ out,
                                                  const float* __restrict__ counts) {
    const int i = blockIdx.x * 256 + threadIdx.x;
    if (i < N_MOLS * HIDDEN) out[i] = out[i] / counts[i / HIDDEN];
}

extern "C" void kernel_launch(void* const* d_in, const int* in_sizes, int n_in,
                              void* d_out, int out_size, void* d_ws, size_t ws_size,
                              hipStream_t stream) {
    const float* fatoms  = (const float*)d_in[0];
    const float* fbonds  = (const float*)d_in[1];
    const int*   agraph  = (const int*)d_in[2];
    const int*   bgraph  = (const int*)d_in[3];
    const int*   mol_ids = (const int*)d_in[4];
    // d_in[5] = n_mols (scalar, fixed at N_MOLS)
    const float* tree    = (const float*)d_in[6];
    const float* W_i     = (const float*)d_in[7];
    const float* W_h     = (const float*)d_in[8];
    const float* W_o     = (const float*)d_in[9];
    const float* b_o     = (const float*)d_in[10];
    float* out = (float*)d_out;

    // workspace layout (f32): gmsg[40000*450] | nei[40000*450] | counts[1000]
    float* gmsg   = (float*)d_ws;
    float* nei    = gmsg + (size_t)N_BONDS * HIDDEN;
    float* counts = nei + (size_t)N_BONDS * HIDDEN;

    (void)hipMemsetAsync(d_out, 0, (size_t)N_MOLS * HIDDEN * sizeof(float), stream);
    (void)hipMemsetAsync(counts, 0, N_MOLS * sizeof(float), stream);

    const dim3 blk(256);
    const dim3 gB((N_BONDS + BM - 1) / BM, (HIDDEN + BN - 1) / BN);
    const dim3 gA((N_ATOMS + BM - 1) / BM, (HIDDEN + BN - 1) / BN);

    // graph_message = relu(fbonds @ W_i^T)
    gemm2<0><<<gB, blk, 0, stream>>>(fbonds, BOND_FD, W_i, BOND_FD, BOND_FD,
                                     nullptr, 0, nullptr, 0, 0,
                                     nullptr, nullptr, gmsg, N_BONDS, HIDDEN);

    for (int it = 0; it < 5; ++it) {  // DEPTH-1 message-passing steps
        gather_sum<<<N_BONDS, blk, 0, stream>>>(bgraph, tree, gmsg, nei);
        // graph_message = relu(fbonds@W_i^T + nei@W_h^T)  (binput recomputed as seg-0)
        gemm2<0><<<gB, blk, 0, stream>>>(fbonds, BOND_FD, W_i, BOND_FD, BOND_FD,
                                         nei, HIDDEN, W_h, HIDDEN, HIDDEN,
                                         nullptr, nullptr, gmsg, N_BONDS, HIDDEN);
    }

    // atom aggregation + output head, fused with molecule-sum via atomics
    gather_sum<<<N_ATOMS, blk, 0, stream>>>(agraph, tree, gmsg, nei);
    gemm2<1><<<gA, blk, 0, stream>>>(fatoms, ATOM_FD, W_o, WO_LD, ATOM_FD,
                                     nei, HIDDEN, W_o + ATOM_FD, WO_LD, HIDDEN,
                                     b_o, mol_ids, out, N_ATOMS, HIDDEN);

    count_atoms<<<(N_ATOMS + 255) / 256, blk, 0, stream>>>(mol_ids, counts);
    div_counts<<<(N_MOLS * HIDDEN + 255) / 256, blk, 0, stream>>>(out, counts);
}

// Round 2
// 1216.090 us; speedup vs baseline: 2.7836x; 2.7836x over previous
//
#include <hip/hip_runtime.h>

#define HIDDEN 450
#define MAX_NB 15
#define N_ATOMS 20000
#define N_BONDS 40000
#define N_MESS  16000
#define N_MOLS  1000
#define KPAD    512     // padded concat-K (40 bond feats + 450 hidden + pad)
#define MSTRIDE 452     // message row stride (elements) — even => 4B-aligned rows

typedef unsigned int uint;
typedef unsigned short ushort;
typedef __bf16 bf16x8 __attribute__((ext_vector_type(8)));
typedef float  f32x4  __attribute__((ext_vector_type(4)));

__device__ __forceinline__ ushort f2bf(float f) {
    uint u = __builtin_bit_cast(uint, f);
    u += 0x7fffu + ((u >> 16) & 1u);     // RNE
    return (ushort)(u >> 16);
}
__device__ __forceinline__ float bfhi(uint w) {  // high bf16 of packed pair
    return __builtin_bit_cast(float, w & 0xffff0000u);
}
__device__ __forceinline__ float bflo(uint w) {
    return __builtin_bit_cast(float, w << 16);
}

#define GLOADLDS16(g, l) __builtin_amdgcn_global_load_lds( \
    (const __attribute__((address_space(1))) void*)(g),    \
    (__attribute__((address_space(3))) void*)(l), 16, 0, 0)

// ---------------- pack kernels (run once per launch) ----------------

__global__ __launch_bounds__(256) void pack_tree(const float* __restrict__ tree,
                                                 ushort* __restrict__ tbuf) {
    const int r = blockIdx.x, t = threadIdx.x;
    if (t < 225) {
        const float2 v = *(const float2*)&tree[(size_t)r * HIDDEN + 2 * t];
        const uint p = (uint)f2bf(v.x) | ((uint)f2bf(v.y) << 16);
        ((uint*)(tbuf + (size_t)r * MSTRIDE))[t] = p;
    }
}

__global__ __launch_bounds__(256) void pack_bonds(const float* __restrict__ fbonds,
                                                  ushort* __restrict__ Abuf) {
    const int r = blockIdx.x * 4 + (threadIdx.x >> 6);
    const int t = threadIdx.x & 63;
    if (r >= N_BONDS) return;
    ushort* row = Abuf + (size_t)r * KPAD;
    if (t < 40) row[t] = f2bf(fbonds[(size_t)r * 40 + t]);
    else        row[t] = 0;                  // cols 40..63 zero (first GEMM K=64)
    if (t >= 40 && t < 62) row[450 + t] = 0; // cols 490..511 zero
}

__global__ __launch_bounds__(256) void pack_atoms(const float* __restrict__ fatoms,
                                                  ushort* __restrict__ Aout) {
    const int r = blockIdx.x * 4 + (threadIdx.x >> 6);
    const int t = threadIdx.x & 63;
    if (r >= N_ATOMS) return;
    ushort* row = Aout + (size_t)r * KPAD;
    if (t < 35)      row[t] = f2bf(fatoms[(size_t)r * 35 + t]);
    else if (t == 35) row[t] = 0;            // col 35 zero (alignment shift)
    if (t >= 36 && t < 62) row[450 + t] = 0; // cols 486..511 zero
}

__global__ __launch_bounds__(256) void pack_w(const float* __restrict__ W_i,
                                              const float* __restrict__ W_h,
                                              const float* __restrict__ W_o,
                                              ushort* __restrict__ Wcat,
                                              ushort* __restrict__ Wocat) {
    const int n = blockIdx.x;  // 0..511
    for (int c = threadIdx.x; c < KPAD; c += 256) {
        float v = 0.0f, vo = 0.0f;
        if (n < HIDDEN) {
            if (c < 40)       v = W_i[(size_t)n * 40 + c];
            else if (c < 490) v = W_h[(size_t)n * HIDDEN + (c - 40)];
            if (c < 35)                vo = W_o[(size_t)n * 485 + c];
            else if (c >= 36 && c < 486) vo = W_o[(size_t)n * 485 + (c - 1)];
        }
        Wcat [(size_t)n * KPAD + c] = f2bf(v);
        Wocat[(size_t)n * KPAD + c] = f2bf(vo);
    }
}

// ---------------- gather: dst_nei = sum_j concat(tree,gmsg)[g[r,j]] ----------------
// ISATOM=0: write into Abuf cols 40..489 (uint idx 20+t). ISATOM=1: Aout cols 36..485.
template <int ISATOM>
__global__ __launch_bounds__(256) void gather_sum(const int* __restrict__ g,
                                                  const ushort* __restrict__ tbuf,
                                                  const ushort* __restrict__ gmsg,
                                                  ushort* __restrict__ dst) {
    const int r = blockIdx.x, t = threadIdx.x;
    if (t >= 225) return;
    const int* gr = g + (size_t)r * MAX_NB;
    float a0 = 0.0f, a1 = 0.0f;
#pragma unroll 1
    for (int j = 0; j < MAX_NB; ++j) {
        const int idx = gr[j];
        const ushort* row = (idx < N_MESS) ? tbuf + (size_t)idx * MSTRIDE
                                           : gmsg + (size_t)(idx - N_MESS) * MSTRIDE;
        const uint w = ((const uint*)row)[t];
        a0 += bflo(w);
        a1 += bfhi(w);
    }
    const uint p = (uint)f2bf(a0) | ((uint)f2bf(a1) << 16);
    ((uint*)(dst + (size_t)r * KPAD))[(ISATOM ? 18 : 20) + t] = p;
}

// ---------------- MFMA GEMM: C[M x 450] = relu(A[M x K] · W[450 x K]^T (+bias)) ----
// MODE 0: store bf16 to gmsg[m*MSTRIDE+n].  MODE 1: atomicAdd f32 to out[mol*450+n].
template <int MODE>
__global__ __launch_bounds__(256) void mfma_gemm(const ushort* __restrict__ A, int M,
                                                 const ushort* __restrict__ W, int K,
                                                 const float* __restrict__ bias,
                                                 const int* __restrict__ mol_ids,
                                                 ushort* __restrict__ gout,
                                                 float* __restrict__ aout) {
    __shared__ ushort At[128 * 32];
    __shared__ ushort Wt[128 * 32];
    const int tid  = threadIdx.x;
    const int lane = tid & 63;
    const int wave = tid >> 6;
    const int wm = (wave >> 1) * 64;   // wave tile origin within 128x128 block
    const int wn = (wave & 1) * 64;
    const int m0 = blockIdx.x * 128;
    const int n0 = blockIdx.y * 128;

    // staging geometry: round r stages bytes [tid*16 + r*4096] of the 8KB tile
    const int ob0 = tid * 16;
    const int row0 = ob0 >> 6, ke0 = ((ob0 >> 4) & 3) * 8;
    const int ob1 = ob0 + 4096;
    const int row1 = ob1 >> 6, ke1 = ((ob1 >> 4) & 3) * 8;
    const int ar0 = min(m0 + row0, M - 1);   // clamp (pad rows read valid mem)
    const int ar1 = min(m0 + row1, M - 1);

    f32x4 acc[4][4];
#pragma unroll
    for (int i = 0; i < 4; ++i)
#pragma unroll
        for (int j = 0; j < 4; ++j) acc[i][j] = (f32x4){0.f, 0.f, 0.f, 0.f};

#pragma unroll 1
    for (int k0 = 0; k0 < K; k0 += 32) {
        GLOADLDS16(A + (size_t)ar0 * KPAD + k0 + ke0, &At[ob0 >> 1]);
        GLOADLDS16(A + (size_t)ar1 * KPAD + k0 + ke1, &At[ob1 >> 1]);
        GLOADLDS16(W + (size_t)(n0 + row0) * KPAD + k0 + ke0, &Wt[ob0 >> 1]);
        GLOADLDS16(W + (size_t)(n0 + row1) * KPAD + k0 + ke1, &Wt[ob1 >> 1]);
        __syncthreads();

        bf16x8 af[4], wf[4];
#pragma unroll
        for (int t = 0; t < 4; ++t)
            af[t] = *(const bf16x8*)&At[(wm + t * 16 + (lane & 15)) * 32 + (lane >> 4) * 8];
#pragma unroll
        for (int t = 0; t < 4; ++t)
            wf[t] = *(const bf16x8*)&Wt[(wn + t * 16 + (lane & 15)) * 32 + (lane >> 4) * 8];
#pragma unroll
        for (int mt = 0; mt < 4; ++mt)
#pragma unroll
            for (int nt = 0; nt < 4; ++nt)
                acc[mt][nt] = __builtin_amdgcn_mfma_f32_16x16x32_bf16(
                    af[mt], wf[nt], acc[mt][nt], 0, 0, 0);
        __syncthreads();
    }

    const int col_l = lane & 15;
    const int rbase = (lane >> 4) * 4;
#pragma unroll
    for (int mt = 0; mt < 4; ++mt) {
#pragma unroll
        for (int nt = 0; nt < 4; ++nt) {
            const int n = n0 + wn + nt * 16 + col_l;
            if (n >= HIDDEN) continue;
#pragma unroll
            for (int reg = 0; reg < 4; ++reg) {
                const int m = m0 + wm + mt * 16 + rbase + reg;
                if (m >= M) continue;
                float v = acc[mt][nt][reg];
                if (MODE == 0) {
                    v = fmaxf(v, 0.0f);
                    gout[(size_t)m * MSTRIDE + n] = f2bf(v);
                } else {
                    v = fmaxf(v + bias[n], 0.0f);
                    atomicAdd(&aout[(size_t)mol_ids[m] * HIDDEN + n], v);
                }
            }
        }
    }
}

// ---------------- molecule mean ----------------
__global__ __launch_bounds__(256) void count_atoms(const int* __restrict__ mol_ids,
                                                   float* __restrict__ counts) {
    const int a = blockIdx.x * 256 + threadIdx.x;
    if (a < N_ATOMS) atomicAdd(&counts[mol_ids[a]], 1.0f);
}
__global__ __launch_bounds__(256) void div_counts(float* __restrict__ out,
                                                  const float* __restrict__ counts) {
    const int i = blockIdx.x * 256 + threadIdx.x;
    if (i < N_MOLS * HIDDEN) out[i] = out[i] / counts[i / HIDDEN];
}

extern "C" void kernel_launch(void* const* d_in, const int* in_sizes, int n_in,
                              void* d_out, int out_size, void* d_ws, size_t ws_size,
                              hipStream_t stream) {
    const float* fatoms  = (const float*)d_in[0];
    const float* fbonds  = (const float*)d_in[1];
    const int*   agraph  = (const int*)d_in[2];
    const int*   bgraph  = (const int*)d_in[3];
    const int*   mol_ids = (const int*)d_in[4];
    const float* tree    = (const float*)d_in[6];
    const float* W_i     = (const float*)d_in[7];
    const float* W_h     = (const float*)d_in[8];
    const float* W_o     = (const float*)d_in[9];
    const float* b_o     = (const float*)d_in[10];
    float* out = (float*)d_out;

    // ws layout (bf16/ushort unless noted)
    ushort* Abuf  = (ushort*)d_ws;                       // 40000 x 512
    ushort* Aout  = Abuf  + (size_t)N_BONDS * KPAD;      // 20000 x 512
    ushort* gmsg  = Aout  + (size_t)N_ATOMS * KPAD;      // 40000 x 452
    ushort* tbuf  = gmsg  + (size_t)N_BONDS * MSTRIDE;   // 16000 x 452
    ushort* Wcat  = tbuf  + (size_t)N_MESS  * MSTRIDE;   // 512 x 512
    ushort* Wocat = Wcat  + (size_t)KPAD * KPAD;         // 512 x 512
    float*  counts = (float*)(Wocat + (size_t)KPAD * KPAD);

    (void)hipMemsetAsync(d_out, 0, (size_t)N_MOLS * HIDDEN * sizeof(float), stream);
    (void)hipMemsetAsync(counts, 0, N_MOLS * sizeof(float), stream);

    const dim3 blk(256);
    pack_tree <<<N_MESS, blk, 0, stream>>>(tree, tbuf);
    pack_bonds<<<(N_BONDS + 3) / 4, blk, 0, stream>>>(fbonds, Abuf);
    pack_atoms<<<(N_ATOMS + 3) / 4, blk, 0, stream>>>(fatoms, Aout);
    pack_w    <<<KPAD, blk, 0, stream>>>(W_i, W_h, W_o, Wcat, Wocat);

    const dim3 gB((N_BONDS + 127) / 128, 4);
    const dim3 gA((N_ATOMS + 127) / 128, 4);

    // gmsg = relu(fbonds @ W_i^T): nei cols 40..63 are zero, so K=64 suffices
    mfma_gemm<0><<<gB, blk, 0, stream>>>(Abuf, N_BONDS, Wcat, 64,
                                         nullptr, nullptr, gmsg, nullptr);
    for (int it = 0; it < 5; ++it) {
        gather_sum<0><<<N_BONDS, blk, 0, stream>>>(bgraph, tbuf, gmsg, Abuf);
        mfma_gemm<0><<<gB, blk, 0, stream>>>(Abuf, N_BONDS, Wcat, KPAD,
                                             nullptr, nullptr, gmsg, nullptr);
    }
    gather_sum<1><<<N_ATOMS, blk, 0, stream>>>(agraph, tbuf, gmsg, Aout);
    mfma_gemm<1><<<gA, blk, 0, stream>>>(Aout, N_ATOMS, Wocat, KPAD,
                                         b_o, mol_ids, nullptr, out);

    count_atoms<<<(N_ATOMS + 255) / 256, blk, 0, stream>>>(mol_ids, counts);
    div_counts <<<(N_MOLS * HIDDEN + 255) / 256, blk, 0, stream>>>(out, counts);
}

// Round 3
// 970.871 us; speedup vs baseline: 3.4867x; 1.2526x over previous
//
#include <hip/hip_runtime.h>

#define HIDDEN 450
#define MAX_NB 15
#define N_ATOMS 20000
#define N_BONDS 40000
#define N_MESS  16000
#define N_MOLS  1000
#define KPAD    512     // padded concat-K: [feat 0..39 | nei 40..489 | pad]
#define MSTRIDE 456     // message row stride = 912B = 57 x 16B chunks

typedef unsigned int uint;
typedef unsigned short ushort;
typedef __bf16 bf16x8 __attribute__((ext_vector_type(8)));
typedef float  f32x4  __attribute__((ext_vector_type(4)));

__device__ __forceinline__ ushort f2bf(float f) {
    uint u = __builtin_bit_cast(uint, f);
    u += 0x7fffu + ((u >> 16) & 1u);     // RNE
    return (ushort)(u >> 16);
}
__device__ __forceinline__ float bfhi(uint w) {
    return __builtin_bit_cast(float, w & 0xffff0000u);
}
__device__ __forceinline__ float bflo(uint w) {
    return __builtin_bit_cast(float, w << 16);
}

#define GLOADLDS16(g, l) __builtin_amdgcn_global_load_lds( \
    (const __attribute__((address_space(1))) void*)(g),    \
    (__attribute__((address_space(3))) void*)(l), 16, 0, 0)

// ---------------- pack kernels (run once per launch) ----------------

__global__ __launch_bounds__(256) void pack_tree(const float* __restrict__ tree,
                                                 ushort* __restrict__ tbuf) {
    const int r = blockIdx.x, t = threadIdx.x;
    if (t < 228) {
        uint p = 0;
        if (t < 225) {
            const float2 v = *(const float2*)&tree[(size_t)r * HIDDEN + 2 * t];
            p = (uint)f2bf(v.x) | ((uint)f2bf(v.y) << 16);
        }
        ((uint*)(tbuf + (size_t)r * MSTRIDE))[t] = p;
    }
}

__global__ __launch_bounds__(256) void pack_bonds(const float* __restrict__ fbonds,
                                                  ushort* __restrict__ Abuf) {
    const int r = blockIdx.x * 4 + (threadIdx.x >> 6);
    const int t = threadIdx.x & 63;
    if (r >= N_BONDS) return;
    ushort* row = Abuf + (size_t)r * KPAD;
    if (t < 40) row[t] = f2bf(fbonds[(size_t)r * 40 + t]);
    else        row[t] = 0;                    // cols 40..63 zero (first GEMM K=64)
    if (t < 16) row[496 + t] = 0;              // cols 496..511 zero
}

__global__ __launch_bounds__(256) void pack_atoms(const float* __restrict__ fatoms,
                                                  ushort* __restrict__ Aout) {
    const int r = blockIdx.x * 4 + (threadIdx.x >> 6);
    const int t = threadIdx.x & 63;
    if (r >= N_ATOMS) return;
    ushort* row = Aout + (size_t)r * KPAD;
    if (t < 40) row[t] = (t < 35) ? f2bf(fatoms[(size_t)r * 35 + t]) : (ushort)0;
    if (t < 16) row[496 + t] = 0;              // cols 496..511 zero
}

__global__ __launch_bounds__(256) void pack_w(const float* __restrict__ W_i,
                                              const float* __restrict__ W_h,
                                              const float* __restrict__ W_o,
                                              ushort* __restrict__ Wcat,
                                              ushort* __restrict__ Wocat) {
    const int n = blockIdx.x;  // 0..511
    for (int c = threadIdx.x; c < KPAD; c += 256) {
        float v = 0.0f, vo = 0.0f;
        if (n < HIDDEN) {
            if (c < 40)       v = W_i[(size_t)n * 40 + c];
            else if (c < 490) v = W_h[(size_t)n * HIDDEN + (c - 40)];
            if (c < 35)       vo = W_o[(size_t)n * 485 + c];
            else if (c >= 40 && c < 490) vo = W_o[(size_t)n * 485 + 35 + (c - 40)];
        }
        Wcat [(size_t)n * KPAD + c] = f2bf(v);
        Wocat[(size_t)n * KPAD + c] = f2bf(vo);
    }
}

// ---------------- gather: dst[r, 40..495] = sum_j concat(tree,gmsg)[g[r,j]] -------
// One wave per row; lane i owns 16B chunk i (i<57); all 15 row-loads in flight.
__global__ __launch_bounds__(256) void gather_sum(const int* __restrict__ g,
                                                  const ushort* __restrict__ tbuf,
                                                  const ushort* __restrict__ gmsg,
                                                  ushort* __restrict__ dst, int nrows) {
    const int r = blockIdx.x * 4 + (threadIdx.x >> 6);
    const int lane = threadIdx.x & 63;
    if (r >= nrows) return;
    const int* gr = g + (size_t)r * MAX_NB;
    int idx[MAX_NB];
#pragma unroll
    for (int j = 0; j < MAX_NB; ++j) idx[j] = gr[j];
    if (lane >= 57) return;
    const int off = lane * 8;              // element offset within message row
    float acc[8] = {};
#pragma unroll
    for (int j = 0; j < MAX_NB; ++j) {
        const ushort* row = (idx[j] < N_MESS)
            ? tbuf + (size_t)idx[j] * MSTRIDE
            : gmsg + (size_t)(idx[j] - N_MESS) * MSTRIDE;
        const uint4 w = *(const uint4*)(row + off);
        acc[0] += bflo(w.x); acc[1] += bfhi(w.x);
        acc[2] += bflo(w.y); acc[3] += bfhi(w.y);
        acc[4] += bflo(w.z); acc[5] += bfhi(w.z);
        acc[6] += bflo(w.w); acc[7] += bfhi(w.w);
    }
    uint4 p;
    p.x = (uint)f2bf(acc[0]) | ((uint)f2bf(acc[1]) << 16);
    p.y = (uint)f2bf(acc[2]) | ((uint)f2bf(acc[3]) << 16);
    p.z = (uint)f2bf(acc[4]) | ((uint)f2bf(acc[5]) << 16);
    p.w = (uint)f2bf(acc[6]) | ((uint)f2bf(acc[7]) << 16);
    *(uint4*)(dst + (size_t)r * KPAD + 40 + off) = p;   // byte off 80+16i: aligned
}

// ---------------- MFMA GEMM: C[M x 450] = relu(A[M x K] · W[450 x K]^T (+bias)) ----
// MODE 0: store bf16 to gmsg[m*MSTRIDE+n].  MODE 1: atomicAdd f32 to out[mol*450+n].
template <int MODE>
__global__ __launch_bounds__(256) void mfma_gemm(const ushort* __restrict__ A, int M,
                                                 const ushort* __restrict__ W, int K,
                                                 const float* __restrict__ bias,
                                                 const int* __restrict__ mol_ids,
                                                 ushort* __restrict__ gout,
                                                 float* __restrict__ aout) {
    __shared__ ushort At[128 * 32];
    __shared__ ushort Wt[128 * 32];
    const int tid  = threadIdx.x;
    const int lane = tid & 63;
    const int wave = tid >> 6;
    const int wm = (wave >> 1) * 64;
    const int wn = (wave & 1) * 64;
    const int m0 = blockIdx.x * 128;
    const int n0 = blockIdx.y * 128;

    const int ob0 = tid * 16;
    const int row0 = ob0 >> 6, ke0 = ((ob0 >> 4) & 3) * 8;
    const int ob1 = ob0 + 4096;
    const int row1 = ob1 >> 6, ke1 = ((ob1 >> 4) & 3) * 8;
    const int ar0 = min(m0 + row0, M - 1);
    const int ar1 = min(m0 + row1, M - 1);

    f32x4 acc[4][4];
#pragma unroll
    for (int i = 0; i < 4; ++i)
#pragma unroll
        for (int j = 0; j < 4; ++j) acc[i][j] = (f32x4){0.f, 0.f, 0.f, 0.f};

#pragma unroll 1
    for (int k0 = 0; k0 < K; k0 += 32) {
        GLOADLDS16(A + (size_t)ar0 * KPAD + k0 + ke0, &At[ob0 >> 1]);
        GLOADLDS16(A + (size_t)ar1 * KPAD + k0 + ke1, &At[ob1 >> 1]);
        GLOADLDS16(W + (size_t)(n0 + row0) * KPAD + k0 + ke0, &Wt[ob0 >> 1]);
        GLOADLDS16(W + (size_t)(n0 + row1) * KPAD + k0 + ke1, &Wt[ob1 >> 1]);
        __syncthreads();

        bf16x8 af[4], wf[4];
#pragma unroll
        for (int t = 0; t < 4; ++t)
            af[t] = *(const bf16x8*)&At[(wm + t * 16 + (lane & 15)) * 32 + (lane >> 4) * 8];
#pragma unroll
        for (int t = 0; t < 4; ++t)
            wf[t] = *(const bf16x8*)&Wt[(wn + t * 16 + (lane & 15)) * 32 + (lane >> 4) * 8];
#pragma unroll
        for (int mt = 0; mt < 4; ++mt)
#pragma unroll
            for (int nt = 0; nt < 4; ++nt)
                acc[mt][nt] = __builtin_amdgcn_mfma_f32_16x16x32_bf16(
                    af[mt], wf[nt], acc[mt][nt], 0, 0, 0);
        __syncthreads();
    }

    const int col_l = lane & 15;
    const int rbase = (lane >> 4) * 4;
#pragma unroll
    for (int mt = 0; mt < 4; ++mt) {
#pragma unroll
        for (int nt = 0; nt < 4; ++nt) {
            const int n = n0 + wn + nt * 16 + col_l;
            if (n >= HIDDEN) continue;
#pragma unroll
            for (int reg = 0; reg < 4; ++reg) {
                const int m = m0 + wm + mt * 16 + rbase + reg;
                if (m >= M) continue;
                float v = acc[mt][nt][reg];
                if (MODE == 0) {
                    v = fmaxf(v, 0.0f);
                    gout[(size_t)m * MSTRIDE + n] = f2bf(v);
                } else {
                    v = fmaxf(v + bias[n], 0.0f);
                    atomicAdd(&aout[(size_t)mol_ids[m] * HIDDEN + n], v);
                }
            }
        }
    }
}

// ---------------- molecule mean ----------------
__global__ __launch_bounds__(256) void count_atoms(const int* __restrict__ mol_ids,
                                                   float* __restrict__ counts) {
    const int a = blockIdx.x * 256 + threadIdx.x;
    if (a < N_ATOMS) atomicAdd(&counts[mol_ids[a]], 1.0f);
}
__global__ __launch_bounds__(256) void div_counts(float* __restrict__ out,
                                                  const float* __restrict__ counts) {
    const int i = blockIdx.x * 256 + threadIdx.x;
    if (i < N_MOLS * HIDDEN) out[i] = out[i] / counts[i / HIDDEN];
}

extern "C" void kernel_launch(void* const* d_in, const int* in_sizes, int n_in,
                              void* d_out, int out_size, void* d_ws, size_t ws_size,
                              hipStream_t stream) {
    const float* fatoms  = (const float*)d_in[0];
    const float* fbonds  = (const float*)d_in[1];
    const int*   agraph  = (const int*)d_in[2];
    const int*   bgraph  = (const int*)d_in[3];
    const int*   mol_ids = (const int*)d_in[4];
    const float* tree    = (const float*)d_in[6];
    const float* W_i     = (const float*)d_in[7];
    const float* W_h     = (const float*)d_in[8];
    const float* W_o     = (const float*)d_in[9];
    const float* b_o     = (const float*)d_in[10];
    float* out = (float*)d_out;

    ushort* Abuf  = (ushort*)d_ws;                       // 40000 x 512
    ushort* Aout  = Abuf  + (size_t)N_BONDS * KPAD;      // 20000 x 512
    ushort* gmsg  = Aout  + (size_t)N_ATOMS * KPAD;      // 40000 x 456
    ushort* tbuf  = gmsg  + (size_t)N_BONDS * MSTRIDE;   // 16000 x 456
    ushort* Wcat  = tbuf  + (size_t)N_MESS  * MSTRIDE;   // 512 x 512
    ushort* Wocat = Wcat  + (size_t)KPAD * KPAD;         // 512 x 512
    float*  counts = (float*)(Wocat + (size_t)KPAD * KPAD);

    (void)hipMemsetAsync(d_out, 0, (size_t)N_MOLS * HIDDEN * sizeof(float), stream);
    (void)hipMemsetAsync(counts, 0, N_MOLS * sizeof(float), stream);
    // zero gmsg pad columns (450..455) once: GEMM only writes n<450
    (void)hipMemsetAsync(gmsg, 0, (size_t)N_BONDS * MSTRIDE * sizeof(ushort), stream);

    const dim3 blk(256);
    pack_tree <<<N_MESS, blk, 0, stream>>>(tree, tbuf);
    pack_bonds<<<(N_BONDS + 3) / 4, blk, 0, stream>>>(fbonds, Abuf);
    pack_atoms<<<(N_ATOMS + 3) / 4, blk, 0, stream>>>(fatoms, Aout);
    pack_w    <<<KPAD, blk, 0, stream>>>(W_i, W_h, W_o, Wcat, Wocat);

    const dim3 gB((N_BONDS + 127) / 128, 4);
    const dim3 gA((N_ATOMS + 127) / 128, 4);

    // gmsg = relu(fbonds @ W_i^T): nei cols 40..63 are zero, so K=64 suffices
    mfma_gemm<0><<<gB, blk, 0, stream>>>(Abuf, N_BONDS, Wcat, 64,
                                         nullptr, nullptr, gmsg, nullptr);
    for (int it = 0; it < 5; ++it) {
        gather_sum<<<(N_BONDS + 3) / 4, blk, 0, stream>>>(bgraph, tbuf, gmsg,
                                                          Abuf, N_BONDS);
        mfma_gemm<0><<<gB, blk, 0, stream>>>(Abuf, N_BONDS, Wcat, KPAD,
                                             nullptr, nullptr, gmsg, nullptr);
    }
    gather_sum<<<(N_ATOMS + 3) / 4, blk, 0, stream>>>(agraph, tbuf, gmsg,
                                                      Aout, N_ATOMS);
    mfma_gemm<1><<<gA, blk, 0, stream>>>(Aout, N_ATOMS, Wocat, KPAD,
                                         b_o, mol_ids, nullptr, out);

    count_atoms<<<(N_ATOMS + 255) / 256, blk, 0, stream>>>(mol_ids, counts);
    div_counts <<<(N_MOLS * HIDDEN + 255) / 256, blk, 0, stream>>>(out, counts);
}